// Round 2
// baseline (416.272 us; speedup 1.0000x reference)
//
#include <hip/hip_runtime.h>
#include <hip/hip_bf16.h>

// TopKRouter: logits = x[16384,4096] @ W[64,4096]^T; softmax; top-2; z_loss.
// v3: exact 3-way bf16 split GEMM, A-operand loaded DIRECT to registers.
//  - gemm: the mfma_32x32x16 A-layout (row=lane&31, k=(lane>>5)*8+j) means a
//    wave-load of 2 dwordx4/lane covers 32 rows x one full 64-B segment, and
//    consecutive k-steps consume adjacent 64-B halves of each 128-B L2 line.
//    So: no LDS staging, no swizzle, ZERO barriers in the K-loop (v2's 16
//    per-panel vmcnt(0) drains with only 64 B/thread in flight were the
//    latency serializer). One __syncthreads remains for the K-half reduce.
//  - epilogue: per-block z partial to d_ws + zreduce kernel (round-1's 210us
//    was 16384 same-address atomicAdds serializing).

typedef __bf16  bf16x8  __attribute__((ext_vector_type(8)));
typedef float   f32x16  __attribute__((ext_vector_type(16)));

#define BS_TOK 16384              // B*S tokens
#define H_DIM  4096
#define E_DIM  64
#define KSPLIT 4
#define KCHUNK (H_DIM / KSPLIT)   // 1024 floats per K-chunk
#define WS_ZBUF_OFF (1536u << 10) // z partials at +1.5 MiB
#define WS_LG_OFF   (2u << 20)    // logits partials at +2 MiB (4 x 4 MiB)

__device__ __forceinline__ void split3(float v, __bf16 &b0, __bf16 &b1, __bf16 &b2) {
    b0 = (__bf16)v;            // top 8 mantissa bits (RN)
    float r = v - (float)b0;   // exact in fp32
    b1 = (__bf16)r;            // next 8 bits
    float r2 = r - (float)b1;  // exact
    b2 = (__bf16)r2;           // v == b0+b1+b2 (within fp32)
}

// Kernel 0: split gate_w into 3 bf16 terms in 32x32x16 MFMA B-frag order.
// frag f = (kb*2 + nt)*3 + term = kb*6 + nt*3 + term; element [f*64 + lane].
// lane holds W_term[n = nt*32 + (lane&31)][k = kb*16 + (lane>>5)*8 + j]
__global__ void prep_w(const float* __restrict__ gw, bf16x8* __restrict__ wb) {
    int idx  = blockIdx.x * blockDim.x + threadIdx.x;   // 0..32767
    int kb   = idx >> 7;
    int rem  = idx & 127;
    int nt   = rem >> 6;
    int lane = rem & 63;
    int n  = nt * 32 + (lane & 31);
    int kk = kb * 16 + ((lane >> 5) << 3);
    const float* p = gw + (size_t)n * H_DIM + kk;
    bf16x8 t0, t1, t2;
#pragma unroll
    for (int j = 0; j < 8; ++j) {
        __bf16 a, b, c;
        split3(p[j], a, b, c);
        t0[j] = a; t1[j] = b; t2[j] = c;
    }
    size_t fb = (size_t)(kb * 2 + nt) * 3;
    wb[(fb + 0) * 64 + lane] = t0;
    wb[(fb + 1) * 64 + lane] = t1;
    wb[(fb + 2) * 64 + lane] = t2;
}

// Kernel 1: block = 256 thr (4 waves), tile M64 x N64 x KCHUNK.
// Wave w: rows (w&1)*32..+32, K-half (w>>1) of the 1024-float chunk
// (512 floats = 32 k-steps of 16). A loaded direct from global into the
// MFMA A-fragment; 1-step register prefetch; barrier-free K-loop.
__global__ __launch_bounds__(256, 4) void gemm_split(
        const float* __restrict__ x, const bf16x8* __restrict__ wb,
        float* __restrict__ lg) {
    __shared__ float red[64 * 64];    // 16 KiB K-half reduce buffer

    int bid = blockIdx.x;
    int mt  = bid >> 2;               // 0..255 (M64 tiles)
    int kc  = bid & 3;                // K-chunk
    int tid = threadIdx.x;
    int w   = tid >> 6;               // wave 0..3
    int l   = tid & 63;
    int m0  = mt * 64;
    int rw  = (w & 1) * 32;           // wave's row base in tile
    int kh  = w >> 1;                 // wave's K-half of chunk

    int row  = rw + (l & 31);         // A row this lane feeds
    int half = l >> 5;                // k sub-offset: (lane>>5)*8

    // lane's A pointer: 32 B contiguous per k-step, stride 64 B between steps
    const float4* gp = (const float4*)(x + (size_t)(m0 + row) * H_DIM
                                         + (size_t)(kc * KCHUNK + kh * 512 + half * 8));
    // W fragments for this wave's absolute k-blocks (kc*64 + kh*32 + ks)
    const bf16x8* wp = wb + (size_t)(kc * 64 + kh * 32) * (6 * 64) + l;

    f32x16 acc0, acc1;
#pragma unroll
    for (int r = 0; r < 16; ++r) { acc0[r] = 0.f; acc1[r] = 0.f; }

    float4 pa = gp[0];                // 1-step prefetch regs
    float4 pb = gp[1];

#pragma unroll 2
    for (int ks = 0; ks < 32; ++ks) {
        float4 ca = pa, cb = pb;
        int nk = (ks + 1) & 31;       // last iter wraps to 0 (harmless reload)
        pa = gp[nk * 4];
        pb = gp[nk * 4 + 1];

        bf16x8 a0, a1, a2;
        float xs[8] = {ca.x, ca.y, ca.z, ca.w, cb.x, cb.y, cb.z, cb.w};
#pragma unroll
        for (int j = 0; j < 8; ++j) {
            __bf16 h0, h1, h2;
            split3(xs[j], h0, h1, h2);
            a0[j] = h0; a1[j] = h1; a2[j] = h2;
        }

        const bf16x8* wq = wp + (size_t)ks * (6 * 64);
        bf16x8 b0 = wq[0 * 64], b1 = wq[1 * 64], b2 = wq[2 * 64];
        bf16x8 b3 = wq[3 * 64], b4 = wq[4 * 64], b5 = wq[5 * 64];

        // experts 0..31
        acc0 = __builtin_amdgcn_mfma_f32_32x32x16_bf16(a0, b0, acc0, 0, 0, 0);
        acc0 = __builtin_amdgcn_mfma_f32_32x32x16_bf16(a1, b0, acc0, 0, 0, 0);
        acc0 = __builtin_amdgcn_mfma_f32_32x32x16_bf16(a2, b0, acc0, 0, 0, 0);
        acc0 = __builtin_amdgcn_mfma_f32_32x32x16_bf16(a0, b1, acc0, 0, 0, 0);
        acc0 = __builtin_amdgcn_mfma_f32_32x32x16_bf16(a1, b1, acc0, 0, 0, 0);
        acc0 = __builtin_amdgcn_mfma_f32_32x32x16_bf16(a0, b2, acc0, 0, 0, 0);
        // experts 32..63
        acc1 = __builtin_amdgcn_mfma_f32_32x32x16_bf16(a0, b3, acc1, 0, 0, 0);
        acc1 = __builtin_amdgcn_mfma_f32_32x32x16_bf16(a1, b3, acc1, 0, 0, 0);
        acc1 = __builtin_amdgcn_mfma_f32_32x32x16_bf16(a2, b3, acc1, 0, 0, 0);
        acc1 = __builtin_amdgcn_mfma_f32_32x32x16_bf16(a0, b4, acc1, 0, 0, 0);
        acc1 = __builtin_amdgcn_mfma_f32_32x32x16_bf16(a1, b4, acc1, 0, 0, 0);
        acc1 = __builtin_amdgcn_mfma_f32_32x32x16_bf16(a0, b5, acc1, 0, 0, 0);
    }

    // --- intra-block K-half reduction via LDS ---
    // C/D layout: col = lane&31, row = (reg&3) + 8*(reg>>2) + 4*(lane>>5)
    int col = l & 31;
    if (kh == 1) {   // waves 2,3 deposit their half
#pragma unroll
        for (int r = 0; r < 16; ++r) {
            int mm = rw + (r & 3) + ((r >> 2) << 3) + (half << 2);
            red[mm * 64 + col]      = acc0[r];
            red[mm * 64 + 32 + col] = acc1[r];
        }
    }
    __syncthreads();
    if (kh == 0) {   // waves 0,1 add and write the K-chunk partial
        size_t obase = (size_t)kc * BS_TOK * E_DIM + (size_t)m0 * E_DIM;
#pragma unroll
        for (int r = 0; r < 16; ++r) {
            int mm = rw + (r & 3) + ((r >> 2) << 3) + (half << 2);
            lg[obase + (size_t)mm * E_DIM + col]
                = acc0[r] + red[mm * 64 + col];
            lg[obase + (size_t)mm * E_DIM + 32 + col]
                = acc1[r] + red[mm * 64 + 32 + col];
        }
    }
}

// Kernel 2: one wave per token. Sum K-partials, softmax, top-2 (low-index
// tie-break), z partial per block (NO same-address atomics).
__global__ __launch_bounds__(256) void epilogue(const float* __restrict__ lg,
                                                float* __restrict__ out,
                                                float* __restrict__ zbuf) {
    __shared__ float zsh[4];
    int lane = threadIdx.x & 63;
    int w    = threadIdx.x >> 6;
    int t    = blockIdx.x * 4 + w;

    float l = 0.f;
#pragma unroll
    for (int s = 0; s < KSPLIT; ++s)
        l += lg[((size_t)s * BS_TOK + t) * E_DIM + lane];

    float z = l * l;
#pragma unroll
    for (int off = 32; off; off >>= 1) z += __shfl_xor(z, off);
    if (lane == 0) zsh[w] = z;

    float m = l;
#pragma unroll
    for (int off = 32; off; off >>= 1) m = fmaxf(m, __shfl_xor(m, off));
    float e = expf(l - m);
    float d = e;
#pragma unroll
    for (int off = 32; off; off >>= 1) d += __shfl_xor(d, off);
    float sc = e / d;

    float s1 = sc; int i1 = lane;
#pragma unroll
    for (int off = 32; off; off >>= 1) {
        float os = __shfl_xor(s1, off); int oi = __shfl_xor(i1, off);
        if (os > s1 || (os == s1 && oi < i1)) { s1 = os; i1 = oi; }
    }
    float sm = (lane == i1) ? -1.0f : sc;
    float s2 = sm; int i2 = lane;
#pragma unroll
    for (int off = 32; off; off >>= 1) {
        float os = __shfl_xor(s2, off); int oi = __shfl_xor(i2, off);
        if (os > s2 || (os == s2 && oi < i2)) { s2 = os; i2 = oi; }
    }

    if (lane == 0) {
        out[2 * t]                  = (float)i1;
        out[2 * t + 1]              = (float)i2;
        out[2 * BS_TOK + 2 * t]     = s1;
        out[2 * BS_TOK + 2 * t + 1] = s2;
    }
    __syncthreads();
    if (threadIdx.x == 0)
        zbuf[blockIdx.x] = zsh[0] + zsh[1] + zsh[2] + zsh[3];
}

// Kernel 3: reduce 4096 z partials -> aux_loss (=0) and z_loss.
__global__ __launch_bounds__(256) void zreduce(const float* __restrict__ zbuf,
                                               float* __restrict__ out) {
    __shared__ float sh[4];
    int tid = threadIdx.x;
    float s = 0.f;
#pragma unroll
    for (int i = 0; i < 16; ++i) s += zbuf[tid + 256 * i];
#pragma unroll
    for (int off = 32; off; off >>= 1) s += __shfl_xor(s, off);
    if ((tid & 63) == 0) sh[tid >> 6] = s;
    __syncthreads();
    if (tid == 0) {
        out[4 * BS_TOK]     = 0.0f;  // aux_loss
        out[4 * BS_TOK + 1] = (sh[0] + sh[1] + sh[2] + sh[3])
                              * (1.0f / (float)(BS_TOK * E_DIM));
    }
}

extern "C" void kernel_launch(void* const* d_in, const int* in_sizes, int n_in,
                              void* d_out, int out_size, void* d_ws, size_t ws_size,
                              hipStream_t stream) {
    const float* x  = (const float*)d_in[0];   // [4,4096,4096] f32
    const float* gw = (const float*)d_in[1];   // [64,4096] f32
    float* out  = (float*)d_out;               // idx | scores | aux | z
    bf16x8* wb  = (bf16x8*)d_ws;                           // 1.5 MiB W frags
    float*  zbf = (float*)((char*)d_ws + WS_ZBUF_OFF);     // 16 KiB z partials
    float*  lg  = (float*)((char*)d_ws + WS_LG_OFF);       // 16 MiB logit partials

    prep_w<<<128, 256, 0, stream>>>(gw, wb);
    gemm_split<<<(BS_TOK / 64) * KSPLIT, 256, 0, stream>>>(x, wb, lg);
    epilogue<<<BS_TOK / 4, 256, 0, stream>>>(lg, out, zbf);
    zreduce<<<1, 256, 0, stream>>>(zbf, out);
}

// Round 3
// 398.930 us; speedup vs baseline: 1.0435x; 1.0435x over previous
//
#include <hip/hip_runtime.h>
#include <hip/hip_bf16.h>

// TopKRouter: logits = x[16384,4096] @ W[64,4096]^T; softmax; top-2; z_loss.
// v4: v2 structure (LDS-staged A, swizzled, proven 397us) + counted-vmcnt
// pipeline (T4): raw s_barrier + s_waitcnt vmcnt(4) instead of __syncthreads'
// vmcnt(0) drain. Next panel's 4 loads/thread stay in flight across BOTH
// barriers -> per-CU in-flight stays ~128 KiB (no 16x/block drain-to-zero
// sawtooth). v3's direct-reg A regressed (-19us): 32-row-scattered wave loads
// cost ~2x L1 segment-cycles and only 32 B/lane MLP.

typedef __bf16  bf16x8  __attribute__((ext_vector_type(8)));
typedef float   f32x16  __attribute__((ext_vector_type(16)));

#define BS_TOK 16384              // B*S tokens
#define H_DIM  4096
#define E_DIM  64
#define KSPLIT 4
#define KCHUNK (H_DIM / KSPLIT)   // 1024
#define NPANEL (KCHUNK / 64)      // 16 panels of 64 floats
#define WS_ZBUF_OFF (1536u << 10) // z partials at +1.5 MiB
#define WS_LG_OFF   (2u << 20)    // logits partials at +2 MiB (4 x 4 MiB)

__device__ __forceinline__ void split3(float v, __bf16 &b0, __bf16 &b1, __bf16 &b2) {
    b0 = (__bf16)v;            // top 8 mantissa bits (RN)
    float r = v - (float)b0;   // exact in fp32
    b1 = (__bf16)r;            // next 8 bits
    float r2 = r - (float)b1;  // exact
    b2 = (__bf16)r2;           // v == b0+b1+b2 (within fp32)
}

__device__ __forceinline__ void async_copy16(const float* gp, float* lp) {
    __builtin_amdgcn_global_load_lds(
        (const __attribute__((address_space(1))) void*)gp,
        (__attribute__((address_space(3))) void*)lp, 16, 0, 0);
}

// Kernel 0: split gate_w into 3 bf16 terms in 32x32x16 MFMA B-frag order.
// frag f = (kb*2 + nt)*3 + term; element [f*64 + lane].
// lane holds W_term[n = nt*32 + (lane&31)][k = kb*16 + (lane>>5)*8 + j]
__global__ void prep_w(const float* __restrict__ gw, bf16x8* __restrict__ wb) {
    int idx  = blockIdx.x * blockDim.x + threadIdx.x;   // 0..32767
    int kb   = idx >> 7;
    int rem  = idx & 127;
    int nt   = rem >> 6;
    int lane = rem & 63;
    int n  = nt * 32 + (lane & 31);
    int kk = kb * 16 + ((lane >> 5) << 3);
    const float* p = gw + (size_t)n * H_DIM + kk;
    bf16x8 t0, t1, t2;
#pragma unroll
    for (int j = 0; j < 8; ++j) {
        __bf16 a, b, c;
        split3(p[j], a, b, c);
        t0[j] = a; t1[j] = b; t2[j] = c;
    }
    size_t fb = (size_t)(kb * 2 + nt) * 3;
    wb[(fb + 0) * 64 + lane] = t0;
    wb[(fb + 1) * 64 + lane] = t1;
    wb[(fb + 2) * 64 + lane] = t2;
}

// Kernel 1: block = 256 thr (4 waves), tile M64 x N64 x KCHUNK.
// Wave w: rows (w&1)*32..+32, K-half (w>>1) of each 64-float panel.
// Panels staged to LDS dbuf via global_load_lds; chunk c of row g stored at
// slot c ^ (g&15) (swizzle on the GLOBAL side; LDS dest linear).
// Sync per panel: s_waitcnt vmcnt(4) + s_barrier (panel p landed, p+1 still
// in flight) ... compute ... s_barrier (buf free) ... stage p+2.
__global__ __launch_bounds__(256, 4) void gemm_split(
        const float* __restrict__ x, const bf16x8* __restrict__ wb,
        float* __restrict__ lg) {
    __shared__ float lds[2 * 4096];   // 2 x 16 KiB panels

    int bid = blockIdx.x;
    int mt  = bid >> 2;               // 0..255 (M64 tiles)
    int kc  = bid & 3;                // K-chunk
    int tid = threadIdx.x;
    int w   = tid >> 6;               // wave 0..3
    int l   = tid & 63;
    int m0  = mt * 64;
    int rw  = (w & 1) * 32;           // wave's row base in tile
    int kh  = w >> 1;                 // wave's K-half of panel

    // --- staging addressing (4 rounds of 16B per thread per panel) ---
    const float* gpan[4];
    int ldso[4];
    int s_slot = l & 15;
#pragma unroll
    for (int r = 0; r < 4; ++r) {
        int g = r * 16 + w * 4 + (l >> 4);          // row in tile 0..63
        int c = s_slot ^ (g & 15);                  // swizzled global chunk
        gpan[r] = x + (size_t)(m0 + g) * H_DIM + kc * KCHUNK + c * 4;
        ldso[r] = (r * 16 + w * 4) * 64;            // wave-uniform float offset
    }

    f32x16 acc0, acc1;
#pragma unroll
    for (int r = 0; r < 16; ++r) { acc0[r] = 0.f; acc1[r] = 0.f; }

    // prologue: stage panel 0 -> buf0, panel 1 -> buf1 (8 loads in flight)
#pragma unroll
    for (int r = 0; r < 4; ++r) async_copy16(gpan[r], &lds[ldso[r]]);
#pragma unroll
    for (int r = 0; r < 4; ++r) async_copy16(gpan[r] + 64, &lds[4096 + ldso[r]]);

    int row  = rw + (l & 31);
    int half = l >> 5;
    int rsw  = row & 15;

#pragma unroll 1
    for (int p = 0; p < NPANEL - 1; ++p) {
        // panel p's 4 loads landed; panel p+1's 4 may stay in flight
        asm volatile("s_waitcnt vmcnt(4)" ::: "memory");
        __builtin_amdgcn_s_barrier();

        int bufo = (p & 1) * 4096;
#pragma unroll
        for (int ks2 = 0; ks2 < 2; ++ks2) {
            int ks     = kh * 2 + ks2;              // k-step in panel 0..3
            int ks_abs = kc * 64 + p * 4 + ks;      // absolute k-block 0..255
            int c0     = ks * 4 + half * 2;
            float4 xa = *(const float4*)&lds[bufo + row * 64 + ((c0 ^ rsw) << 2)];
            float4 xb = *(const float4*)&lds[bufo + row * 64 + (((c0 + 1) ^ rsw) << 2)];
            bf16x8 a0, a1, a2;
            float xs[8] = {xa.x, xa.y, xa.z, xa.w, xb.x, xb.y, xb.z, xb.w};
#pragma unroll
            for (int j = 0; j < 8; ++j) {
                __bf16 h0, h1, h2;
                split3(xs[j], h0, h1, h2);
                a0[j] = h0; a1[j] = h1; a2[j] = h2;
            }
            const bf16x8* wp = wb + (size_t)ks_abs * 6 * 64 + l;
            bf16x8 b0 = wp[0*64], b1 = wp[1*64], b2 = wp[2*64];
            bf16x8 b3 = wp[3*64], b4 = wp[4*64], b5 = wp[5*64];
            acc0 = __builtin_amdgcn_mfma_f32_32x32x16_bf16(a0, b0, acc0, 0, 0, 0);
            acc0 = __builtin_amdgcn_mfma_f32_32x32x16_bf16(a1, b0, acc0, 0, 0, 0);
            acc0 = __builtin_amdgcn_mfma_f32_32x32x16_bf16(a2, b0, acc0, 0, 0, 0);
            acc0 = __builtin_amdgcn_mfma_f32_32x32x16_bf16(a0, b1, acc0, 0, 0, 0);
            acc0 = __builtin_amdgcn_mfma_f32_32x32x16_bf16(a1, b1, acc0, 0, 0, 0);
            acc0 = __builtin_amdgcn_mfma_f32_32x32x16_bf16(a0, b2, acc0, 0, 0, 0);
            acc1 = __builtin_amdgcn_mfma_f32_32x32x16_bf16(a0, b3, acc1, 0, 0, 0);
            acc1 = __builtin_amdgcn_mfma_f32_32x32x16_bf16(a1, b3, acc1, 0, 0, 0);
            acc1 = __builtin_amdgcn_mfma_f32_32x32x16_bf16(a2, b3, acc1, 0, 0, 0);
            acc1 = __builtin_amdgcn_mfma_f32_32x32x16_bf16(a0, b4, acc1, 0, 0, 0);
            acc1 = __builtin_amdgcn_mfma_f32_32x32x16_bf16(a1, b4, acc1, 0, 0, 0);
            acc1 = __builtin_amdgcn_mfma_f32_32x32x16_bf16(a0, b5, acc1, 0, 0, 0);
        }

        // all waves done reading buf[p&1] -> safe to overwrite with panel p+2
        __builtin_amdgcn_s_barrier();
        if (p + 2 < NPANEL) {
#pragma unroll
            for (int r = 0; r < 4; ++r)
                async_copy16(gpan[r] + (p + 2) * 64, &lds[(p & 1) * 4096 + ldso[r]]);
        }
    }

    // peeled last panel (p = NPANEL-1): only its own 4 loads remain
    asm volatile("s_waitcnt vmcnt(0)" ::: "memory");
    __builtin_amdgcn_s_barrier();
    {
        const int p    = NPANEL - 1;
        const int bufo = (p & 1) * 4096;
#pragma unroll
        for (int ks2 = 0; ks2 < 2; ++ks2) {
            int ks     = kh * 2 + ks2;
            int ks_abs = kc * 64 + p * 4 + ks;
            int c0     = ks * 4 + half * 2;
            float4 xa = *(const float4*)&lds[bufo + row * 64 + ((c0 ^ rsw) << 2)];
            float4 xb = *(const float4*)&lds[bufo + row * 64 + (((c0 + 1) ^ rsw) << 2)];
            bf16x8 a0, a1, a2;
            float xs[8] = {xa.x, xa.y, xa.z, xa.w, xb.x, xb.y, xb.z, xb.w};
#pragma unroll
            for (int j = 0; j < 8; ++j) {
                __bf16 h0, h1, h2;
                split3(xs[j], h0, h1, h2);
                a0[j] = h0; a1[j] = h1; a2[j] = h2;
            }
            const bf16x8* wp = wb + (size_t)ks_abs * 6 * 64 + l;
            bf16x8 b0 = wp[0*64], b1 = wp[1*64], b2 = wp[2*64];
            bf16x8 b3 = wp[3*64], b4 = wp[4*64], b5 = wp[5*64];
            acc0 = __builtin_amdgcn_mfma_f32_32x32x16_bf16(a0, b0, acc0, 0, 0, 0);
            acc0 = __builtin_amdgcn_mfma_f32_32x32x16_bf16(a1, b0, acc0, 0, 0, 0);
            acc0 = __builtin_amdgcn_mfma_f32_32x32x16_bf16(a2, b0, acc0, 0, 0, 0);
            acc0 = __builtin_amdgcn_mfma_f32_32x32x16_bf16(a0, b1, acc0, 0, 0, 0);
            acc0 = __builtin_amdgcn_mfma_f32_32x32x16_bf16(a1, b1, acc0, 0, 0, 0);
            acc0 = __builtin_amdgcn_mfma_f32_32x32x16_bf16(a0, b2, acc0, 0, 0, 0);
            acc1 = __builtin_amdgcn_mfma_f32_32x32x16_bf16(a0, b3, acc1, 0, 0, 0);
            acc1 = __builtin_amdgcn_mfma_f32_32x32x16_bf16(a1, b3, acc1, 0, 0, 0);
            acc1 = __builtin_amdgcn_mfma_f32_32x32x16_bf16(a2, b3, acc1, 0, 0, 0);
            acc1 = __builtin_amdgcn_mfma_f32_32x32x16_bf16(a0, b4, acc1, 0, 0, 0);
            acc1 = __builtin_amdgcn_mfma_f32_32x32x16_bf16(a1, b4, acc1, 0, 0, 0);
            acc1 = __builtin_amdgcn_mfma_f32_32x32x16_bf16(a0, b5, acc1, 0, 0, 0);
        }
    }

    // --- intra-block K-half reduction via LDS (deposit into buf0 region;
    // last compute read buf1, and buf0 reads finished before the p=15 barrier)
    // C/D layout: col = lane&31, row = (reg&3) + 8*(reg>>2) + 4*(lane>>5)
    int col = l & 31;
    if (kh == 1) {   // waves 2,3 deposit their half
#pragma unroll
        for (int r = 0; r < 16; ++r) {
            int mm = rw + (r & 3) + ((r >> 2) << 3) + (half << 2);
            lds[mm * 64 + col]      = acc0[r];
            lds[mm * 64 + 32 + col] = acc1[r];
        }
    }
    __syncthreads();
    if (kh == 0) {   // waves 0,1 add and write the K-chunk partial
        size_t obase = (size_t)kc * BS_TOK * E_DIM + (size_t)m0 * E_DIM;
#pragma unroll
        for (int r = 0; r < 16; ++r) {
            int mm = rw + (r & 3) + ((r >> 2) << 3) + (half << 2);
            lg[obase + (size_t)mm * E_DIM + col]
                = acc0[r] + lds[mm * 64 + col];
            lg[obase + (size_t)mm * E_DIM + 32 + col]
                = acc1[r] + lds[mm * 64 + 32 + col];
        }
    }
}

// Kernel 2: one wave per token. Sum K-partials, softmax, top-2 (low-index
// tie-break), z partial per block (NO same-address atomics).
__global__ __launch_bounds__(256) void epilogue(const float* __restrict__ lg,
                                                float* __restrict__ out,
                                                float* __restrict__ zbuf) {
    __shared__ float zsh[4];
    int lane = threadIdx.x & 63;
    int w    = threadIdx.x >> 6;
    int t    = blockIdx.x * 4 + w;

    float l = 0.f;
#pragma unroll
    for (int s = 0; s < KSPLIT; ++s)
        l += lg[((size_t)s * BS_TOK + t) * E_DIM + lane];

    float z = l * l;
#pragma unroll
    for (int off = 32; off; off >>= 1) z += __shfl_xor(z, off);
    if (lane == 0) zsh[w] = z;

    float m = l;
#pragma unroll
    for (int off = 32; off; off >>= 1) m = fmaxf(m, __shfl_xor(m, off));
    float e = expf(l - m);
    float d = e;
#pragma unroll
    for (int off = 32; off; off >>= 1) d += __shfl_xor(d, off);
    float sc = e / d;

    float s1 = sc; int i1 = lane;
#pragma unroll
    for (int off = 32; off; off >>= 1) {
        float os = __shfl_xor(s1, off); int oi = __shfl_xor(i1, off);
        if (os > s1 || (os == s1 && oi < i1)) { s1 = os; i1 = oi; }
    }
    float sm = (lane == i1) ? -1.0f : sc;
    float s2 = sm; int i2 = lane;
#pragma unroll
    for (int off = 32; off; off >>= 1) {
        float os = __shfl_xor(s2, off); int oi = __shfl_xor(i2, off);
        if (os > s2 || (os == s2 && oi < i2)) { s2 = os; i2 = oi; }
    }

    if (lane == 0) {
        out[2 * t]                  = (float)i1;
        out[2 * t + 1]              = (float)i2;
        out[2 * BS_TOK + 2 * t]     = s1;
        out[2 * BS_TOK + 2 * t + 1] = s2;
    }
    __syncthreads();
    if (threadIdx.x == 0)
        zbuf[blockIdx.x] = zsh[0] + zsh[1] + zsh[2] + zsh[3];
}

// Kernel 3: reduce 4096 z partials -> aux_loss (=0) and z_loss.
__global__ __launch_bounds__(256) void zreduce(const float* __restrict__ zbuf,
                                               float* __restrict__ out) {
    __shared__ float sh[4];
    int tid = threadIdx.x;
    float s = 0.f;
#pragma unroll
    for (int i = 0; i < 16; ++i) s += zbuf[tid + 256 * i];
#pragma unroll
    for (int off = 32; off; off >>= 1) s += __shfl_xor(s, off);
    if ((tid & 63) == 0) sh[tid >> 6] = s;
    __syncthreads();
    if (tid == 0) {
        out[4 * BS_TOK]     = 0.0f;  // aux_loss
        out[4 * BS_TOK + 1] = (sh[0] + sh[1] + sh[2] + sh[3])
                              * (1.0f / (float)(BS_TOK * E_DIM));
    }
}

extern "C" void kernel_launch(void* const* d_in, const int* in_sizes, int n_in,
                              void* d_out, int out_size, void* d_ws, size_t ws_size,
                              hipStream_t stream) {
    const float* x  = (const float*)d_in[0];   // [4,4096,4096] f32
    const float* gw = (const float*)d_in[1];   // [64,4096] f32
    float* out  = (float*)d_out;               // idx | scores | aux | z
    bf16x8* wb  = (bf16x8*)d_ws;                           // 1.5 MiB W frags
    float*  zbf = (float*)((char*)d_ws + WS_ZBUF_OFF);     // 16 KiB z partials
    float*  lg  = (float*)((char*)d_ws + WS_LG_OFF);       // 16 MiB logit partials

    prep_w<<<128, 256, 0, stream>>>(gw, wb);
    gemm_split<<<(BS_TOK / 64) * KSPLIT, 256, 0, stream>>>(x, wb, lg);
    epilogue<<<BS_TOK / 4, 256, 0, stream>>>(lg, out, zbf);
    zreduce<<<1, 256, 0, stream>>>(zbf, out);
}